// Round 12
// baseline (469.582 us; speedup 1.0000x reference)
//
#include <hip/hip_runtime.h>
#include <hip/hip_bf16.h>

// GATv2 x3 layers, MI355X. f32 in/out; edge_index int32.
// R24: head-clustered aggregation. k_agg2 = one wave per (head,node),
// head-major index + XCD-contiguous swizzle -> per-XCD xs-gather working set
// = one head's 256B row-slices (2.56MB, L2-resident; R22 showed the fused
// all-heads k_agg fetched 101MB = L2 thrash). 8-wide batched gathers (R23's
// proven ILP fix). Partials atomicAdd into d_out (doubles as accumulator:
// exactly NN*CD, write-only until end -> ws stays 35.6MB; R17's 48MB
// faulted). k_comb reads accum, RE-ZEROES it in place (replaces all
// per-layer memsets), writes mean+bias+ELU. Setup: two memsets merged
// (adjacent buffers); k_eacsr+k_loopattr fused into k_eal (one gather pass).
// k_score/k_xl byte-identical to R23 (best: 461.6us).

#define NN 10000    // nodes
#define NE 200000   // edges
#define ND 128      // node dim (layer 0 input)
#define ED 16       // edge dim
#define CD 64       // conv dim (per head)
#define NH 5        // heads
#define HC 320      // NH*CD
#define EF 210000   // NE + NN (with self loops)
#define EFP 210048  // EF padded to 64
#define NEG 0.2f
#define PB 824      // k_score p-blocks per head (824*256 >= EF)
#define TOTB 4120   // PB*NH total k_score blocks = 8 XCDs * 515
#define PERX 515    // k_score work items per XCD
#define NW_AGG 50000   // NH*NN agg waves (head-major)
#define BL_AGG 12504   // 8*1563 blocks of 4 waves, guard g>=NW_AGG
#define PERXA 1563     // agg blocks per XCD

typedef float f2 __attribute__((ext_vector_type(2)));

// ---- CSR build: count ----
__global__ void k_count(const int* __restrict__ dst, int* __restrict__ deg) {
  int e = blockIdx.x * blockDim.x + threadIdx.x;
  if (e >= NE) return;
  atomicAdd(&deg[dst[e]], 1);
}

// ---- CSR build: exclusive scan (single block, 1024 threads x 10 elems) ----
__global__ __launch_bounds__(1024) void k_scan(const int* __restrict__ deg,
                                               int* __restrict__ rowptr) {
  __shared__ int part[1024];
  int t = threadIdx.x;
  int base = t * 10;
  int local[10];
  int s = 0;
  #pragma unroll
  for (int j = 0; j < 10; j++) {
    int i = base + j;
    local[j] = (i < NN) ? deg[i] : 0;
    s += local[j];
  }
  part[t] = s;
  __syncthreads();
  for (int off = 1; off < 1024; off <<= 1) {
    int v = (t >= off) ? part[t - off] : 0;
    __syncthreads();
    part[t] += v;
    __syncthreads();
  }
  int prefix = (t > 0) ? part[t - 1] : 0;
  #pragma unroll
  for (int j = 0; j < 10; j++) {
    int i = base + j;
    if (i < NN) rowptr[i] = prefix;
    prefix += local[j];
  }
  if (t == 1023) rowptr[NN] = prefix;
}

// ---- CSR build: fill ----
__global__ void k_fill(const int* __restrict__ ei, const int* __restrict__ rowptr,
                       int* __restrict__ cursor, int* __restrict__ csr_eid,
                       int* __restrict__ csr_src, int* __restrict__ csr_dst) {
  int e = blockIdx.x * blockDim.x + threadIdx.x;
  if (e >= NE) return;
  int d = ei[NE + e];
  int slot = atomicAdd(&cursor[d], 1);
  int pos = rowptr[d] + slot;
  csr_eid[pos] = e;
  csr_src[pos] = ei[e];
  csr_dst[pos] = d;
}

// ---- ea_csr permute + loop_attr mean, fused (one gather pass) ----
__global__ __launch_bounds__(256) void k_eal(const int* __restrict__ csr_eid,
                                             const float* __restrict__ eattr,
                                             const int* __restrict__ rowptr,
                                             float* __restrict__ ea_csr,
                                             float* __restrict__ loop_attr) {
  int wave = threadIdx.x >> 6, lane = threadIdx.x & 63;
  int d = blockIdx.x * 4 + wave;
  if (d >= NN) return;
  int g = lane >> 4, k = lane & 15;
  int b = rowptr[d], n = rowptr[d + 1] - b;
  float s = 0.f;
  for (int i = g; i < n; i += 4) {
    float v = eattr[(size_t)csr_eid[b + i] * ED + k];
    ea_csr[(size_t)(b + i) * ED + k] = v;
    s += v;
  }
  s += __shfl_xor(s, 16, 64);
  s += __shfl_xor(s, 32, 64);
  if (g == 0) loop_attr[d * ED + k] = s / fmaxf((float)n, 1.0f);
}

// ---- Wpk for ALL 3 layers in one dispatch ----
// Wpk[l][((h*32 + cp)*16 + k)*2 + j] = We_l[k][h*64 + 2*cp + j]
__global__ void k_wet3(const float* __restrict__ We0, const float* __restrict__ We1,
                       const float* __restrict__ We2, float* __restrict__ Wpk) {
  int i = blockIdx.x * blockDim.x + threadIdx.x;
  if (i >= 3 * ED * HC) return;
  int l = i / (ED * HC);
  int r = i - l * (ED * HC);
  const float* We = (l == 0) ? We0 : (l == 1) ? We1 : We2;
  int j  = r & 1;
  int k  = (r >> 1) & 15;
  int cp = (r >> 5) & 31;
  int h  = r >> 10;
  Wpk[i] = We[k * HC + h * CD + cp * 2 + j];
}

// ---- xl = h @ Wl + bl  (node-major xl[node][hc], contiguous 1280B rows) ----
template <int D>
__global__ __launch_bounds__(320) void k_xl(const float* __restrict__ h,
                                            const float* __restrict__ Wl,
                                            const float* __restrict__ bl,
                                            float* __restrict__ xl) {
  constexpr int NPB = 8;
  int node0 = blockIdx.x * NPB;
  int t = threadIdx.x;  // output column 0..319
  float acc[NPB];
  #pragma unroll
  for (int i = 0; i < NPB; i++) acc[i] = 0.f;
  for (int k = 0; k < D; k += 4) {
    float w0 = Wl[(k + 0) * HC + t];
    float w1 = Wl[(k + 1) * HC + t];
    float w2 = Wl[(k + 2) * HC + t];
    float w3 = Wl[(k + 3) * HC + t];
    #pragma unroll
    for (int i = 0; i < NPB; i++) {
      float4 hv = *(const float4*)(h + (size_t)(node0 + i) * D + k);
      acc[i] += hv.x * w0 + hv.y * w1 + hv.z * w2 + hv.w * w3;
    }
  }
  float bv = bl[t];
  #pragma unroll
  for (int i = 0; i < NPB; i++)
    xl[(size_t)(node0 + i) * HC + t] = acc[i] + bv;
}

// ---- scores: ONE THREAD PER (EDGE, HEAD); writes w = exp(clamped score).
// R14 packed body; node-major xl addressing; head-clustered XCD mapping
// (per-XCD line working set = one head's 2.56MB of lines -> L2-resident).
__global__ __launch_bounds__(256) void k_score(
    const int* __restrict__ csr_src, const int* __restrict__ csr_dst,
    const float* __restrict__ ea_csr, const float* __restrict__ loop_attr,
    const float* __restrict__ xl, const float* __restrict__ Wpk,
    const float* __restrict__ att, float* __restrict__ wP) {
  int bid = blockIdx.x;                       // 0..TOTB-1
  int w = (bid & 7) * PERX + (bid >> 3);      // work item, contiguous per XCD
  int h = w / PB;                             // head (uniform, magic-div)
  int lb = w - h * PB;                        // p-slice within head
  int p = lb * 256 + threadIdx.x;
  if (p >= EF) return;
  int s, d;
  const float* ea;
  if (p < NE) { s = csr_src[p]; d = csr_dst[p]; ea = ea_csr + (size_t)p * ED; }
  else        { s = d = p - NE; ea = loop_attr + (size_t)(p - NE) * ED; }
  float eas[16];
  {
    const float4* q = (const float4*)ea;
    float4 t0 = q[0], t1 = q[1], t2 = q[2], t3 = q[3];
    eas[0] = t0.x;  eas[1] = t0.y;  eas[2] = t0.z;  eas[3] = t0.w;
    eas[4] = t1.x;  eas[5] = t1.y;  eas[6] = t1.z;  eas[7] = t1.w;
    eas[8] = t2.x;  eas[9] = t2.y;  eas[10] = t2.z; eas[11] = t2.w;
    eas[12] = t3.x; eas[13] = t3.y; eas[14] = t3.z; eas[15] = t3.w;
  }
  const float* xsrow = xl + (size_t)s * HC + h * CD;   // node-major
  const float* xdrow = xl + (size_t)d * HC + h * CD;
  const f2* wp = (const f2*)Wpk + (size_t)h * (CD / 2) * ED;  // [32 pairs][16 k]
  const f2* ap = (const f2*)(att + (size_t)h * CD);           // pairs contiguous
  f2 sc2 = {0.f, 0.f};
  const f2 zero = {0.f, 0.f};
  #pragma unroll 4
  for (int cb = 0; cb < CD; cb += 4) {  // 2 channel-pairs per iter, 16 iters
    int cp = cb >> 1;
    float4 xs4 = *(const float4*)(xsrow + cb);
    float4 xd4 = *(const float4*)(xdrow + cb);
    const f2* w0 = wp + (size_t)cp * ED;
    const f2* w1 = w0 + ED;
    f2 z0 = f2{xs4.x, xs4.y} + f2{xd4.x, xd4.y};   // v_pk_add_f32
    f2 z1 = f2{xs4.z, xs4.w} + f2{xd4.z, xd4.w};
    #pragma unroll
    for (int k = 0; k < ED; k++) {                 // 2x v_pk_fma_f32 per k
      z0 += w0[k] * eas[k];
      z1 += w1[k] * eas[k];
    }
    // leaky: max(z,0) + NEG*min(z,0)  (packed, branchless, exact)
    z0 = __builtin_elementwise_max(z0, zero) + NEG * __builtin_elementwise_min(z0, zero);
    z1 = __builtin_elementwise_max(z1, zero) + NEG * __builtin_elementwise_min(z1, zero);
    sc2 += z0 * ap[cp];
    sc2 += z1 * ap[cp + 1];
  }
  float sc = sc2.x + sc2.y;
  sc = fminf(fmaxf(sc, -60.f), 60.f);  // clamp never binds for sane inputs
  wP[(size_t)h * EFP + p] = __expf(sc);
}

// ---- aggregation: ONE WAVE PER (HEAD, NODE), head-clustered XCD mapping ----
// Per-XCD xs-gather working set = one head's 256B row-slices (2.56MB,
// L2-resident). 8-wide batched gathers (8 VMEM in flight). atomicAdd of
// acc/dn into accum[d][c] (pre-zeroed by k_comb / setup memset).
__global__ __launch_bounds__(256) void k_agg2(
    const int* __restrict__ csr_src, const int* __restrict__ rowptr,
    const float* __restrict__ wP, const float* __restrict__ xl,
    float* __restrict__ accum) {
  int bid = blockIdx.x;
  int b2 = (bid & 7) * PERXA + (bid >> 3);   // contiguous per XCD
  int wv = threadIdx.x >> 6, lane = threadIdx.x & 63;
  int g = b2 * 4 + wv;                        // global wave id, head-major
  if (g >= NW_AGG) return;
  int h = g / NN;                             // uniform (magic-div)
  int d = g - h * NN;
  int b = rowptr[d], pe = rowptr[d + 1];
  const float* sp = wP + (size_t)h * EFP;
  const float* xlh = xl + h * CD + lane;      // node-major, head slice
  // self loop init
  float dn = sp[NE + d];
  float acc = dn * xlh[(size_t)d * HC];
  int p = b;
  // 8-edge batches: all 8 gathers independent and in flight together
  for (; p + 8 <= pe; p += 8) {
    int s0 = csr_src[p + 0], s1 = csr_src[p + 1];
    int s2 = csr_src[p + 2], s3 = csr_src[p + 3];
    int s4 = csr_src[p + 4], s5 = csr_src[p + 5];
    int s6 = csr_src[p + 6], s7 = csr_src[p + 7];
    float w0 = sp[p + 0], w1 = sp[p + 1], w2 = sp[p + 2], w3 = sp[p + 3];
    float w4 = sp[p + 4], w5 = sp[p + 5], w6 = sp[p + 6], w7 = sp[p + 7];
    float x0 = xlh[(size_t)s0 * HC];
    float x1 = xlh[(size_t)s1 * HC];
    float x2 = xlh[(size_t)s2 * HC];
    float x3 = xlh[(size_t)s3 * HC];
    float x4 = xlh[(size_t)s4 * HC];
    float x5 = xlh[(size_t)s5 * HC];
    float x6 = xlh[(size_t)s6 * HC];
    float x7 = xlh[(size_t)s7 * HC];
    dn += ((w0 + w1) + (w2 + w3)) + ((w4 + w5) + (w6 + w7));
    acc += ((w0 * x0 + w1 * x1) + (w2 * x2 + w3 * x3)) +
           ((w4 * x4 + w5 * x5) + (w6 * x6 + w7 * x7));
  }
  for (; p + 4 <= pe; p += 4) {
    int s0 = csr_src[p + 0], s1 = csr_src[p + 1];
    int s2 = csr_src[p + 2], s3 = csr_src[p + 3];
    float w0 = sp[p + 0], w1 = sp[p + 1], w2 = sp[p + 2], w3 = sp[p + 3];
    float x0 = xlh[(size_t)s0 * HC];
    float x1 = xlh[(size_t)s1 * HC];
    float x2 = xlh[(size_t)s2 * HC];
    float x3 = xlh[(size_t)s3 * HC];
    dn += (w0 + w1) + (w2 + w3);
    acc += (w0 * x0 + w1 * x1) + (w2 * x2 + w3 * x3);
  }
  for (; p < pe; p++) {
    int s0 = csr_src[p];
    float w0 = sp[p];
    dn += w0;
    acc += w0 * xlh[(size_t)s0 * HC];
  }
  atomicAdd(&accum[(size_t)d * CD + lane], acc / dn);
}

// ---- combine: out = elu(accum/NH + bias); re-zeroes accum for next layer --
// NOTE: accum/out intentionally NOT __restrict__ (l=2 passes same buffer).
__global__ __launch_bounds__(256) void k_comb(float* accum,
                                              const float* __restrict__ bias,
                                              float* out) {
  int idx = blockIdx.x * blockDim.x + threadIdx.x;  // d*CD + c
  if (idx >= NN * CD) return;
  int c = idx & (CD - 1);
  float v = accum[idx];
  accum[idx] = 0.f;                          // ready for next layer's atomics
  v = v * (1.0f / NH) + bias[c];
  v = v > 0.f ? v : expm1f(v);
  out[idx] = v;
}

static inline size_t aln(size_t x) { return (x + 255) & ~(size_t)255; }

extern "C" void kernel_launch(void* const* d_in, const int* in_sizes, int n_in,
                              void* d_out, int out_size, void* d_ws, size_t ws_size,
                              hipStream_t stream) {
  const float* x = (const float*)d_in[0];
  const int* ei = (const int*)d_in[1];      // [2, NE]: src row then dst row
  const float* eattr = (const float*)d_in[2];

  char* w = (char*)d_ws;
  int* degi      = (int*)w;                 w += aln(NN * 4);
  int* cursor    = (int*)w;                 w += aln(NN * 4);
  int* rowptr    = (int*)w;                 w += aln((NN + 1) * 4);
  int* csr_eid   = (int*)w;                 w += aln((size_t)NE * 4);
  int* csr_src   = (int*)w;                 w += aln((size_t)NE * 4);
  int* csr_dst   = (int*)w;                 w += aln((size_t)NE * 4);
  float* loop_attr = (float*)w;             w += aln((size_t)NN * ED * 4);
  float* ea_csr  = (float*)w;               w += aln((size_t)NE * ED * 4);
  float* xl      = (float*)w;               w += aln((size_t)NN * HC * 4);
  float* wPbuf   = (float*)w;               w += aln((size_t)NH * EFP * 4);
  float* Wpk     = (float*)w;               w += aln((size_t)3 * ED * HC * 4);
  float* hbuf    = (float*)w;               w += aln((size_t)NN * CD * 4);
  float* accum   = (float*)d_out;           // NN*CD scratch, write-only until end

  // graph structure + permuted edge attrs + all-layer Wpk (layer-invariant)
  hipMemsetAsync(degi, 0, 2 * aln(NN * 4), stream);   // degi + cursor (adjacent)
  hipMemsetAsync(accum, 0, (size_t)NN * CD * 4, stream);
  k_count<<<(NE + 255) / 256, 256, 0, stream>>>(ei + NE, degi);
  k_scan<<<1, 1024, 0, stream>>>(degi, rowptr);
  k_fill<<<(NE + 255) / 256, 256, 0, stream>>>(ei, rowptr, cursor, csr_eid, csr_src, csr_dst);
  k_eal<<<(NN + 3) / 4, 256, 0, stream>>>(csr_eid, eattr, rowptr, ea_csr, loop_attr);
  k_wet3<<<(3 * ED * HC + 255) / 256, 256, 0, stream>>>(
      (const float*)d_in[5], (const float*)d_in[10], (const float*)d_in[15], Wpk);

  for (int l = 0; l < 3; l++) {
    const float* Wl  = (const float*)d_in[3 + 5 * l];
    const float* bl  = (const float*)d_in[4 + 5 * l];
    const float* att = (const float*)d_in[6 + 5 * l];
    const float* b   = (const float*)d_in[7 + 5 * l];

    if (l == 0) k_xl<ND><<<NN / 8, 320, 0, stream>>>(x, Wl, bl, xl);
    else        k_xl<CD><<<NN / 8, 320, 0, stream>>>(hbuf, Wl, bl, xl);

    k_score<<<TOTB, 256, 0, stream>>>(csr_src, csr_dst, ea_csr, loop_attr,
                                      xl, Wpk + (size_t)l * ED * HC, att, wPbuf);

    k_agg2<<<BL_AGG, 256, 0, stream>>>(csr_src, rowptr, wPbuf, xl, accum);

    float* dst_out = (l < 2) ? hbuf : (float*)d_out;
    k_comb<<<(NN * CD + 255) / 256, 256, 0, stream>>>(accum, b, dst_out);
  }
}

// Round 13
// 457.214 us; speedup vs baseline: 1.0270x; 1.0270x over previous
//
#include <hip/hip_runtime.h>
#include <hip/hip_bf16.h>

// GATv2 x3 layers, MI355X. f32 in/out; edge_index int32.
// R25: R23 base (best 461.6us) + runtime ws_size branch:
//   big ws  -> k_agg2p: one wave per (head,node), head-clustered XCD swizzle
//              (per-XCD xs working set = one 2.56MB head slice; R22 measured
//              the unclustered agg at 101MB FETCH / 1.56 TB/s = L3-line
//              bound), 8-wide batched gathers, NON-ATOMIC coalesced partial
//              writes [NH][NN][CD]; k_combp streams mean+bias+ELU.
//              (R24 proved clustering passes but cross-XCD atomicAdds ate
//              the win; R21==R22 flake-proof says R17's "ws overflow" may
//              have been a flake -> probe the buffer safely via the branch.)
//   small ws-> R23's k_agg path byte-identical (no risk).
// k_score/k_xl/setup byte-identical to R23.

#define NN 10000    // nodes
#define NE 200000   // edges
#define ND 128      // node dim (layer 0 input)
#define ED 16       // edge dim
#define CD 64       // conv dim (per head)
#define NH 5        // heads
#define HC 320      // NH*CD
#define EF 210000   // NE + NN (with self loops)
#define EFP 210048  // EF padded to 64
#define NEG 0.2f
#define PB 824      // k_score p-blocks per head (824*256 >= EF)
#define TOTB 4120   // PB*NH total k_score blocks = 8 XCDs * 515
#define PERX 515    // k_score work items per XCD
#define NW_AGG 50000   // NH*NN agg waves (head-major)
#define BL_AGG 12504   // 8*1563 blocks of 4 waves, guard g>=NW_AGG
#define PERXA 1563     // agg blocks per XCD

typedef float f2 __attribute__((ext_vector_type(2)));

// ---- CSR build: count ----
__global__ void k_count(const int* __restrict__ dst, int* __restrict__ deg) {
  int e = blockIdx.x * blockDim.x + threadIdx.x;
  if (e >= NE) return;
  atomicAdd(&deg[dst[e]], 1);
}

// ---- CSR build: exclusive scan (single block, 1024 threads x 10 elems) ----
__global__ __launch_bounds__(1024) void k_scan(const int* __restrict__ deg,
                                               int* __restrict__ rowptr) {
  __shared__ int part[1024];
  int t = threadIdx.x;
  int base = t * 10;
  int local[10];
  int s = 0;
  #pragma unroll
  for (int j = 0; j < 10; j++) {
    int i = base + j;
    local[j] = (i < NN) ? deg[i] : 0;
    s += local[j];
  }
  part[t] = s;
  __syncthreads();
  for (int off = 1; off < 1024; off <<= 1) {
    int v = (t >= off) ? part[t - off] : 0;
    __syncthreads();
    part[t] += v;
    __syncthreads();
  }
  int prefix = (t > 0) ? part[t - 1] : 0;
  #pragma unroll
  for (int j = 0; j < 10; j++) {
    int i = base + j;
    if (i < NN) rowptr[i] = prefix;
    prefix += local[j];
  }
  if (t == 1023) rowptr[NN] = prefix;
}

// ---- CSR build: fill ----
__global__ void k_fill(const int* __restrict__ ei, const int* __restrict__ rowptr,
                       int* __restrict__ cursor, int* __restrict__ csr_eid,
                       int* __restrict__ csr_src, int* __restrict__ csr_dst) {
  int e = blockIdx.x * blockDim.x + threadIdx.x;
  if (e >= NE) return;
  int d = ei[NE + e];
  int slot = atomicAdd(&cursor[d], 1);
  int pos = rowptr[d] + slot;
  csr_eid[pos] = e;
  csr_src[pos] = ei[e];
  csr_dst[pos] = d;
}

// ---- ea_csr permute + loop_attr mean, fused (one gather pass) ----
__global__ __launch_bounds__(256) void k_eal(const int* __restrict__ csr_eid,
                                             const float* __restrict__ eattr,
                                             const int* __restrict__ rowptr,
                                             float* __restrict__ ea_csr,
                                             float* __restrict__ loop_attr) {
  int wave = threadIdx.x >> 6, lane = threadIdx.x & 63;
  int d = blockIdx.x * 4 + wave;
  if (d >= NN) return;
  int g = lane >> 4, k = lane & 15;
  int b = rowptr[d], n = rowptr[d + 1] - b;
  float s = 0.f;
  for (int i = g; i < n; i += 4) {
    float v = eattr[(size_t)csr_eid[b + i] * ED + k];
    ea_csr[(size_t)(b + i) * ED + k] = v;
    s += v;
  }
  s += __shfl_xor(s, 16, 64);
  s += __shfl_xor(s, 32, 64);
  if (g == 0) loop_attr[d * ED + k] = s / fmaxf((float)n, 1.0f);
}

// ---- Wpk for ALL 3 layers in one dispatch ----
// Wpk[l][((h*32 + cp)*16 + k)*2 + j] = We_l[k][h*64 + 2*cp + j]
__global__ void k_wet3(const float* __restrict__ We0, const float* __restrict__ We1,
                       const float* __restrict__ We2, float* __restrict__ Wpk) {
  int i = blockIdx.x * blockDim.x + threadIdx.x;
  if (i >= 3 * ED * HC) return;
  int l = i / (ED * HC);
  int r = i - l * (ED * HC);
  const float* We = (l == 0) ? We0 : (l == 1) ? We1 : We2;
  int j  = r & 1;
  int k  = (r >> 1) & 15;
  int cp = (r >> 5) & 31;
  int h  = r >> 10;
  Wpk[i] = We[k * HC + h * CD + cp * 2 + j];
}

// ---- xl = h @ Wl + bl  (node-major xl[node][hc], contiguous 1280B rows) ----
template <int D>
__global__ __launch_bounds__(320) void k_xl(const float* __restrict__ h,
                                            const float* __restrict__ Wl,
                                            const float* __restrict__ bl,
                                            float* __restrict__ xl) {
  constexpr int NPB = 8;
  int node0 = blockIdx.x * NPB;
  int t = threadIdx.x;  // output column 0..319
  float acc[NPB];
  #pragma unroll
  for (int i = 0; i < NPB; i++) acc[i] = 0.f;
  for (int k = 0; k < D; k += 4) {
    float w0 = Wl[(k + 0) * HC + t];
    float w1 = Wl[(k + 1) * HC + t];
    float w2 = Wl[(k + 2) * HC + t];
    float w3 = Wl[(k + 3) * HC + t];
    #pragma unroll
    for (int i = 0; i < NPB; i++) {
      float4 hv = *(const float4*)(h + (size_t)(node0 + i) * D + k);
      acc[i] += hv.x * w0 + hv.y * w1 + hv.z * w2 + hv.w * w3;
    }
  }
  float bv = bl[t];
  #pragma unroll
  for (int i = 0; i < NPB; i++)
    xl[(size_t)(node0 + i) * HC + t] = acc[i] + bv;
}

// ---- scores: ONE THREAD PER (EDGE, HEAD); writes w = exp(clamped score).
// R14 packed body; node-major xl addressing; head-clustered XCD mapping
// (per-XCD line working set = one head's 2.56MB of lines -> L2-resident).
__global__ __launch_bounds__(256) void k_score(
    const int* __restrict__ csr_src, const int* __restrict__ csr_dst,
    const float* __restrict__ ea_csr, const float* __restrict__ loop_attr,
    const float* __restrict__ xl, const float* __restrict__ Wpk,
    const float* __restrict__ att, float* __restrict__ wP) {
  int bid = blockIdx.x;                       // 0..TOTB-1
  int w = (bid & 7) * PERX + (bid >> 3);      // work item, contiguous per XCD
  int h = w / PB;                             // head (uniform, magic-div)
  int lb = w - h * PB;                        // p-slice within head
  int p = lb * 256 + threadIdx.x;
  if (p >= EF) return;
  int s, d;
  const float* ea;
  if (p < NE) { s = csr_src[p]; d = csr_dst[p]; ea = ea_csr + (size_t)p * ED; }
  else        { s = d = p - NE; ea = loop_attr + (size_t)(p - NE) * ED; }
  float eas[16];
  {
    const float4* q = (const float4*)ea;
    float4 t0 = q[0], t1 = q[1], t2 = q[2], t3 = q[3];
    eas[0] = t0.x;  eas[1] = t0.y;  eas[2] = t0.z;  eas[3] = t0.w;
    eas[4] = t1.x;  eas[5] = t1.y;  eas[6] = t1.z;  eas[7] = t1.w;
    eas[8] = t2.x;  eas[9] = t2.y;  eas[10] = t2.z; eas[11] = t2.w;
    eas[12] = t3.x; eas[13] = t3.y; eas[14] = t3.z; eas[15] = t3.w;
  }
  const float* xsrow = xl + (size_t)s * HC + h * CD;   // node-major
  const float* xdrow = xl + (size_t)d * HC + h * CD;
  const f2* wp = (const f2*)Wpk + (size_t)h * (CD / 2) * ED;  // [32 pairs][16 k]
  const f2* ap = (const f2*)(att + (size_t)h * CD);           // pairs contiguous
  f2 sc2 = {0.f, 0.f};
  const f2 zero = {0.f, 0.f};
  #pragma unroll 4
  for (int cb = 0; cb < CD; cb += 4) {  // 2 channel-pairs per iter, 16 iters
    int cp = cb >> 1;
    float4 xs4 = *(const float4*)(xsrow + cb);
    float4 xd4 = *(const float4*)(xdrow + cb);
    const f2* w0 = wp + (size_t)cp * ED;
    const f2* w1 = w0 + ED;
    f2 z0 = f2{xs4.x, xs4.y} + f2{xd4.x, xd4.y};   // v_pk_add_f32
    f2 z1 = f2{xs4.z, xs4.w} + f2{xd4.z, xd4.w};
    #pragma unroll
    for (int k = 0; k < ED; k++) {                 // 2x v_pk_fma_f32 per k
      z0 += w0[k] * eas[k];
      z1 += w1[k] * eas[k];
    }
    // leaky: max(z,0) + NEG*min(z,0)  (packed, branchless, exact)
    z0 = __builtin_elementwise_max(z0, zero) + NEG * __builtin_elementwise_min(z0, zero);
    z1 = __builtin_elementwise_max(z1, zero) + NEG * __builtin_elementwise_min(z1, zero);
    sc2 += z0 * ap[cp];
    sc2 += z1 * ap[cp + 1];
  }
  float sc = sc2.x + sc2.y;
  sc = fminf(fmaxf(sc, -60.f), 60.f);  // clamp never binds for sane inputs
  wP[(size_t)h * EFP + p] = __expf(sc);
}

// ---- aggregation A (fallback, R23): block per node, wave per head ----
__global__ __launch_bounds__(320) void k_agg(
    const int* __restrict__ csr_src, const int* __restrict__ rowptr,
    const float* __restrict__ wP, const float* __restrict__ xl,
    const float* __restrict__ bias, float* __restrict__ out) {
  __shared__ float s_v[NH][CD];
  int h = threadIdx.x >> 6, lane = threadIdx.x & 63;
  int d = blockIdx.x;
  int b = rowptr[d], pe = rowptr[d + 1];
  const float* sp = wP + (size_t)h * EFP;
  const float* xlh = xl + h * CD + lane;               // node-major layout
  float dn = sp[NE + d];
  float acc = dn * xlh[(size_t)d * HC];
  int p = b;
  for (; p + 8 <= pe; p += 8) {
    int s0 = csr_src[p + 0], s1 = csr_src[p + 1];
    int s2 = csr_src[p + 2], s3 = csr_src[p + 3];
    int s4 = csr_src[p + 4], s5 = csr_src[p + 5];
    int s6 = csr_src[p + 6], s7 = csr_src[p + 7];
    float w0 = sp[p + 0], w1 = sp[p + 1], w2 = sp[p + 2], w3 = sp[p + 3];
    float w4 = sp[p + 4], w5 = sp[p + 5], w6 = sp[p + 6], w7 = sp[p + 7];
    float x0 = xlh[(size_t)s0 * HC];
    float x1 = xlh[(size_t)s1 * HC];
    float x2 = xlh[(size_t)s2 * HC];
    float x3 = xlh[(size_t)s3 * HC];
    float x4 = xlh[(size_t)s4 * HC];
    float x5 = xlh[(size_t)s5 * HC];
    float x6 = xlh[(size_t)s6 * HC];
    float x7 = xlh[(size_t)s7 * HC];
    dn += ((w0 + w1) + (w2 + w3)) + ((w4 + w5) + (w6 + w7));
    acc += ((w0 * x0 + w1 * x1) + (w2 * x2 + w3 * x3)) +
           ((w4 * x4 + w5 * x5) + (w6 * x6 + w7 * x7));
  }
  for (; p + 4 <= pe; p += 4) {
    int s0 = csr_src[p + 0], s1 = csr_src[p + 1];
    int s2 = csr_src[p + 2], s3 = csr_src[p + 3];
    float w0 = sp[p + 0], w1 = sp[p + 1], w2 = sp[p + 2], w3 = sp[p + 3];
    float x0 = xlh[(size_t)s0 * HC];
    float x1 = xlh[(size_t)s1 * HC];
    float x2 = xlh[(size_t)s2 * HC];
    float x3 = xlh[(size_t)s3 * HC];
    dn += (w0 + w1) + (w2 + w3);
    acc += (w0 * x0 + w1 * x1) + (w2 * x2 + w3 * x3);
  }
  for (; p < pe; p++) {
    int s0 = csr_src[p];
    float w0 = sp[p];
    dn += w0;
    acc += w0 * xlh[(size_t)s0 * HC];
  }
  s_v[h][lane] = acc / dn;
  __syncthreads();
  if (h == 0) {
    float v = s_v[0][lane] + s_v[1][lane] + s_v[2][lane] + s_v[3][lane] + s_v[4][lane];
    v = v * (1.0f / NH) + bias[lane];
    v = v > 0.f ? v : expm1f(v);
    out[(size_t)d * CD + lane] = v;
  }
}

// ---- aggregation B: ONE WAVE PER (HEAD,NODE), head-clustered, NON-ATOMIC --
// Per-XCD xs working set = one head's 2.56MB of aligned 4-line slices.
// Writes partial[h][d][c] = acc/dn coalesced (g = h*NN + d is wave id).
__global__ __launch_bounds__(256) void k_agg2p(
    const int* __restrict__ csr_src, const int* __restrict__ rowptr,
    const float* __restrict__ wP, const float* __restrict__ xl,
    float* __restrict__ partial) {
  int bid = blockIdx.x;
  int b2 = (bid & 7) * PERXA + (bid >> 3);   // contiguous per XCD
  int wv = threadIdx.x >> 6, lane = threadIdx.x & 63;
  int g = b2 * 4 + wv;                        // head-major wave id
  if (g >= NW_AGG) return;
  int h = g / NN;                             // uniform (magic-div)
  int d = g - h * NN;
  int b = rowptr[d], pe = rowptr[d + 1];
  const float* sp = wP + (size_t)h * EFP;
  const float* xlh = xl + h * CD + lane;      // node-major, head slice
  float dn = sp[NE + d];
  float acc = dn * xlh[(size_t)d * HC];
  int p = b;
  for (; p + 8 <= pe; p += 8) {
    int s0 = csr_src[p + 0], s1 = csr_src[p + 1];
    int s2 = csr_src[p + 2], s3 = csr_src[p + 3];
    int s4 = csr_src[p + 4], s5 = csr_src[p + 5];
    int s6 = csr_src[p + 6], s7 = csr_src[p + 7];
    float w0 = sp[p + 0], w1 = sp[p + 1], w2 = sp[p + 2], w3 = sp[p + 3];
    float w4 = sp[p + 4], w5 = sp[p + 5], w6 = sp[p + 6], w7 = sp[p + 7];
    float x0 = xlh[(size_t)s0 * HC];
    float x1 = xlh[(size_t)s1 * HC];
    float x2 = xlh[(size_t)s2 * HC];
    float x3 = xlh[(size_t)s3 * HC];
    float x4 = xlh[(size_t)s4 * HC];
    float x5 = xlh[(size_t)s5 * HC];
    float x6 = xlh[(size_t)s6 * HC];
    float x7 = xlh[(size_t)s7 * HC];
    dn += ((w0 + w1) + (w2 + w3)) + ((w4 + w5) + (w6 + w7));
    acc += ((w0 * x0 + w1 * x1) + (w2 * x2 + w3 * x3)) +
           ((w4 * x4 + w5 * x5) + (w6 * x6 + w7 * x7));
  }
  for (; p + 4 <= pe; p += 4) {
    int s0 = csr_src[p + 0], s1 = csr_src[p + 1];
    int s2 = csr_src[p + 2], s3 = csr_src[p + 3];
    float w0 = sp[p + 0], w1 = sp[p + 1], w2 = sp[p + 2], w3 = sp[p + 3];
    float x0 = xlh[(size_t)s0 * HC];
    float x1 = xlh[(size_t)s1 * HC];
    float x2 = xlh[(size_t)s2 * HC];
    float x3 = xlh[(size_t)s3 * HC];
    dn += (w0 + w1) + (w2 + w3);
    acc += (w0 * x0 + w1 * x1) + (w2 * x2 + w3 * x3);
  }
  for (; p < pe; p++) {
    int s0 = csr_src[p];
    float w0 = sp[p];
    dn += w0;
    acc += w0 * xlh[(size_t)s0 * HC];
  }
  partial[(size_t)g * CD + lane] = acc / dn;  // coalesced 256B per wave
}

// ---- combine from partials: out = elu(mean_h partial + bias) ----
__global__ __launch_bounds__(256) void k_combp(const float* __restrict__ partial,
                                               const float* __restrict__ bias,
                                               float* __restrict__ out) {
  int idx = blockIdx.x * blockDim.x + threadIdx.x;  // d*CD + c
  if (idx >= NN * CD) return;
  int c = idx & (CD - 1);
  float v = partial[idx];
  #pragma unroll
  for (int h = 1; h < NH; h++)
    v += partial[(size_t)h * NN * CD + idx];
  v = v * (1.0f / NH) + bias[c];
  v = v > 0.f ? v : expm1f(v);
  out[idx] = v;
}

static inline size_t aln(size_t x) { return (x + 255) & ~(size_t)255; }

extern "C" void kernel_launch(void* const* d_in, const int* in_sizes, int n_in,
                              void* d_out, int out_size, void* d_ws, size_t ws_size,
                              hipStream_t stream) {
  const float* x = (const float*)d_in[0];
  const int* ei = (const int*)d_in[1];      // [2, NE]: src row then dst row
  const float* eattr = (const float*)d_in[2];

  char* w = (char*)d_ws;
  int* degi      = (int*)w;                 w += aln(NN * 4);
  int* cursor    = (int*)w;                 w += aln(NN * 4);
  int* rowptr    = (int*)w;                 w += aln((NN + 1) * 4);
  int* csr_eid   = (int*)w;                 w += aln((size_t)NE * 4);
  int* csr_src   = (int*)w;                 w += aln((size_t)NE * 4);
  int* csr_dst   = (int*)w;                 w += aln((size_t)NE * 4);
  float* loop_attr = (float*)w;             w += aln((size_t)NN * ED * 4);
  float* ea_csr  = (float*)w;               w += aln((size_t)NE * ED * 4);
  float* xl      = (float*)w;               w += aln((size_t)NN * HC * 4);
  float* wPbuf   = (float*)w;               w += aln((size_t)NH * EFP * 4);
  float* Wpk     = (float*)w;               w += aln((size_t)3 * ED * HC * 4);
  float* hbuf    = (float*)w;               w += aln((size_t)NN * CD * 4);
  float* partial = (float*)w;               w += aln((size_t)NH * NN * CD * 4);
  size_t needed = (size_t)(w - (char*)d_ws);
  bool big_ws = (ws_size >= needed);        // runtime probe; safe either way

  // graph structure + permuted edge attrs + all-layer Wpk (layer-invariant)
  hipMemsetAsync(degi, 0, 2 * aln(NN * 4), stream);   // degi + cursor (adjacent)
  k_count<<<(NE + 255) / 256, 256, 0, stream>>>(ei + NE, degi);
  k_scan<<<1, 1024, 0, stream>>>(degi, rowptr);
  k_fill<<<(NE + 255) / 256, 256, 0, stream>>>(ei, rowptr, cursor, csr_eid, csr_src, csr_dst);
  k_eal<<<(NN + 3) / 4, 256, 0, stream>>>(csr_eid, eattr, rowptr, ea_csr, loop_attr);
  k_wet3<<<(3 * ED * HC + 255) / 256, 256, 0, stream>>>(
      (const float*)d_in[5], (const float*)d_in[10], (const float*)d_in[15], Wpk);

  for (int l = 0; l < 3; l++) {
    const float* Wl  = (const float*)d_in[3 + 5 * l];
    const float* bl  = (const float*)d_in[4 + 5 * l];
    const float* att = (const float*)d_in[6 + 5 * l];
    const float* b   = (const float*)d_in[7 + 5 * l];

    if (l == 0) k_xl<ND><<<NN / 8, 320, 0, stream>>>(x, Wl, bl, xl);
    else        k_xl<CD><<<NN / 8, 320, 0, stream>>>(hbuf, Wl, bl, xl);

    k_score<<<TOTB, 256, 0, stream>>>(csr_src, csr_dst, ea_csr, loop_attr,
                                      xl, Wpk + (size_t)l * ED * HC, att, wPbuf);

    float* dst_out = (l < 2) ? hbuf : (float*)d_out;
    if (big_ws) {
      k_agg2p<<<BL_AGG, 256, 0, stream>>>(csr_src, rowptr, wPbuf, xl, partial);
      k_combp<<<(NN * CD + 255) / 256, 256, 0, stream>>>(partial, b, dst_out);
    } else {
      k_agg<<<NN, 320, 0, stream>>>(csr_src, rowptr, wPbuf, xl, b, dst_out);
    }
  }
}